// Round 1
// baseline (907.822 us; speedup 1.0000x reference)
//
#include <hip/hip_runtime.h>
#include <math.h>

// Problem constants (fixed by reference)
#define BB   2
#define TT   4096            // tokens per batch
#define NT   (BB*TT)         // 8192 total rows
#define DD   1024
#define CQ   128             // k_query dim
#define TK   8               // top_k
#define NCH  16              // s-chunks for sim kernel
#define SC   (TT/NCH)        // 256 s per chunk

// ---------------------------------------------------------------------------
// top-8 sorted insert, comparator = (value desc, index asc) == jax.lax.top_k
// ---------------------------------------------------------------------------
__device__ __forceinline__ void topk8_insert(float (&v)[TK], int (&ix)[TK],
                                             float val, int idx) {
    float cv = val; int ci = idx;
#pragma unroll
    for (int i = 0; i < TK; ++i) {
        bool sw = (cv > v[i]) || (cv == v[i] && ci < ix[i]);
        float tv = v[i]; int ti = ix[i];
        v[i]  = sw ? cv : tv;  ix[i] = sw ? ci : ti;
        cv    = sw ? tv : cv;  ci    = sw ? ti : ci;
    }
}

// ---------------------------------------------------------------------------
// K1: q = x@Wq + bq ; k = x@Wk + bk   (f32, W broadcast via uniform loads)
// grid (NT/256, 16), block 256. blockIdx.y picks 16 cols of combined [q|k].
// ---------------------------------------------------------------------------
__global__ __launch_bounds__(256) void proj_kernel(
    const float* __restrict__ x,
    const float* __restrict__ Wq, const float* __restrict__ bq,
    const float* __restrict__ Wk, const float* __restrict__ bk,
    float* __restrict__ q, float* __restrict__ k)
{
    int row = blockIdx.x * 256 + threadIdx.x;        // 0..NT-1
    int cc  = blockIdx.y * 16;                       // combined col 0..255
    bool isK = cc >= CQ;
    const float* W    = isK ? Wk : Wq;
    const float* bias = isK ? bk : bq;
    int c0 = isK ? cc - CQ : cc;

    float acc[16];
#pragma unroll
    for (int j = 0; j < 16; ++j) acc[j] = 0.f;

    const float* xr = x + (size_t)row * DD;
    for (int d0 = 0; d0 < DD; d0 += 4) {
        float4 xv = *reinterpret_cast<const float4*>(xr + d0);
        const float* w0 = W + (size_t)d0 * CQ + c0;
#pragma unroll
        for (int j = 0; j < 16; ++j) {
            acc[j] = fmaf(xv.x, w0[j],        acc[j]);
            acc[j] = fmaf(xv.y, w0[CQ + j],   acc[j]);
            acc[j] = fmaf(xv.z, w0[2*CQ + j], acc[j]);
            acc[j] = fmaf(xv.w, w0[3*CQ + j], acc[j]);
        }
    }
    float* outp = (isK ? k : q) + (size_t)row * CQ + c0;
#pragma unroll
    for (int j = 0; j < 16; ++j) outp[j] = acc[j] + bias[c0 + j];
}

// ---------------------------------------------------------------------------
// K1b: gates = sigmoid(x@Wg + bg)   one wave per row
// ---------------------------------------------------------------------------
__global__ __launch_bounds__(256) void gate_kernel(
    const float* __restrict__ x, const float* __restrict__ Wg,
    const float* __restrict__ bg, float* __restrict__ gout)
{
    int wave = threadIdx.x >> 6, lane = threadIdx.x & 63;
    int row  = blockIdx.x * 4 + wave;
    const float* xr = x + (size_t)row * DD;
    float s = 0.f;
#pragma unroll
    for (int i = 0; i < 4; ++i) {
        int d = (i * 64 + lane) * 4;
        float4 xv = *reinterpret_cast<const float4*>(xr + d);
        float4 wv = *reinterpret_cast<const float4*>(Wg + d);
        s = fmaf(xv.x, wv.x, s); s = fmaf(xv.y, wv.y, s);
        s = fmaf(xv.z, wv.z, s); s = fmaf(xv.w, wv.w, s);
    }
#pragma unroll
    for (int off = 32; off; off >>= 1) s += __shfl_xor(s, off);
    if (lane == 0) gout[row] = 1.f / (1.f + expf(-(s + bg[0])));
}

// ---------------------------------------------------------------------------
// K2: sim row chunk + partial top-8. thread = query, s-chunk = blockIdx.y.
// q row in VGPRs; k row addresses wave-uniform (same cache line all lanes).
// ---------------------------------------------------------------------------
__global__ __launch_bounds__(64, 2) void simtopk_kernel(
    const float* __restrict__ q, const float* __restrict__ kmat,
    const float* __restrict__ gates, const float* __restrict__ am,
    float* __restrict__ pv, int* __restrict__ pi)
{
    int t  = blockIdx.x * 64 + threadIdx.x;   // global query 0..NT-1
    int ch = blockIdx.y;
    int b  = t >> 12;                          // uniform per block (64 | 4096)
    int s0 = ch * SC;

    float4 qv[CQ / 4];
    const float4* qp = reinterpret_cast<const float4*>(q + (size_t)t * CQ);
#pragma unroll
    for (int m = 0; m < CQ / 4; ++m) qv[m] = qp[m];

    float gate = gates[t];
    float mq   = am[t];

    float v[TK]; int ix[TK];
#pragma unroll
    for (int j = 0; j < TK; ++j) { v[j] = -3.0e38f; ix[j] = 0; }

    const float scale = 0.08838834764831845f;  // 1/sqrt(128)

    for (int si = 0; si < SC; ++si) {
        int s = s0 + si;
        const float4* kp =
            reinterpret_cast<const float4*>(kmat + ((size_t)(b * TT + s)) * CQ);
        float a0 = 0.f, a1 = 0.f, a2 = 0.f, a3 = 0.f;
#pragma unroll
        for (int m = 0; m < CQ / 4; ++m) {
            float4 kv = kp[m];
            a0 = fmaf(qv[m].x, kv.x, a0);
            a1 = fmaf(qv[m].y, kv.y, a1);
            a2 = fmaf(qv[m].z, kv.z, a2);
            a3 = fmaf(qv[m].w, kv.w, a3);
        }
        float val = ((a0 + a1) + (a2 + a3)) * scale;
        float ms  = am[b * TT + s];
        if (mq * ms == 0.f) val = -1e9f;
        val *= gate;
        if (val > v[TK-1] || (val == v[TK-1] && s < ix[TK-1]))
            topk8_insert(v, ix, val, s);
    }

    int base = (t * NCH + ch) * TK;
#pragma unroll
    for (int j = 0; j < TK; ++j) { pv[base + j] = v[j]; pi[base + j] = ix[j]; }
}

// ---------------------------------------------------------------------------
// K3: merge NCH partial top-8 lists -> final top-8; write idx (as float),
// values, and gather x rows. block per query, 256 threads.
// ---------------------------------------------------------------------------
__global__ __launch_bounds__(256) void merge_gather_kernel(
    const float* __restrict__ x,
    const float* __restrict__ pv, const int* __restrict__ pi,
    float* __restrict__ out_g, float* __restrict__ out_i,
    float* __restrict__ out_v)
{
    int t = blockIdx.x;
    __shared__ int sidx[TK];

    if (threadIdx.x == 0) {
        float v[TK]; int ix[TK];
#pragma unroll
        for (int j = 0; j < TK; ++j) { v[j] = -3.0e38f; ix[j] = 0; }
        const float* pvb = pv + (size_t)t * NCH * TK;
        const int*   pib = pi + (size_t)t * NCH * TK;
        for (int c = 0; c < NCH * TK; ++c) {
            float val = pvb[c]; int s = pib[c];
            if (val > v[TK-1] || (val == v[TK-1] && s < ix[TK-1]))
                topk8_insert(v, ix, val, s);
        }
#pragma unroll
        for (int j = 0; j < TK; ++j) {
            out_i[t * TK + j] = (float)ix[j];
            out_v[t * TK + j] = v[j];
            sidx[j] = ix[j];
        }
    }
    __syncthreads();

    int b = t >> 12;
#pragma unroll
    for (int j = 0; j < TK; ++j) {
        int row = sidx[j];
        float4 val = *reinterpret_cast<const float4*>(
            x + ((size_t)(b * TT + row)) * DD + threadIdx.x * 4);
        *reinterpret_cast<float4*>(
            out_g + ((size_t)(t * TK + j)) * DD + threadIdx.x * 4) = val;
    }
}

// ---------------------------------------------------------------------------
extern "C" void kernel_launch(void* const* d_in, const int* in_sizes, int n_in,
                              void* d_out, int out_size, void* d_ws, size_t ws_size,
                              hipStream_t stream) {
    const float* x  = (const float*)d_in[0];
    const float* am = (const float*)d_in[1];
    const float* Wq = (const float*)d_in[2];
    const float* bq = (const float*)d_in[3];
    const float* Wk = (const float*)d_in[4];
    const float* bk = (const float*)d_in[5];
    const float* Wg = (const float*)d_in[6];
    const float* bg = (const float*)d_in[7];

    float* ws = (float*)d_ws;
    float* q  = ws;                              // NT*CQ      = 1048576
    float* k  = ws + 1048576;                    // NT*CQ      = 1048576
    float* g  = ws + 2097152;                    // NT         = 8192
    float* pv = ws + 2105344;                    // NT*NCH*TK  = 1048576
    int*   pi = (int*)(ws + 3153920);            // NT*NCH*TK  = 1048576

    float* out_g = (float*)d_out;                // [B,T,K,D] = 67108864
    float* out_i = out_g + 67108864;             // [B,T,K]   = 65536 (as float)
    float* out_v = out_i + 65536;                // [B,T,K]   = 65536

    proj_kernel<<<dim3(NT / 256, 16), 256, 0, stream>>>(x, Wq, bq, Wk, bk, q, k);
    gate_kernel<<<NT / 4, 256, 0, stream>>>(x, Wg, bg, g);
    simtopk_kernel<<<dim3(NT / 64, NCH), 64, 0, stream>>>(q, k, g, am, pv, pi);
    merge_gather_kernel<<<NT, 256, 0, stream>>>(x, pv, pi, out_g, out_i, out_v);
}

// Round 2
// 726.100 us; speedup vs baseline: 1.2503x; 1.2503x over previous
//
#include <hip/hip_runtime.h>
#include <math.h>

// Problem constants (fixed by reference)
#define BB   2
#define TT   4096            // tokens per batch
#define NT   (BB*TT)         // 8192 total rows
#define DD   1024
#define CQ   128             // k_query dim
#define TK   8               // top_k
#define NCH  16              // s-chunks for sim kernel
#define SC   (TT/NCH)        // 256 s per chunk

// ---------------------------------------------------------------------------
// top-8 sorted insert, comparator = (value desc, index asc) == jax.lax.top_k
// ---------------------------------------------------------------------------
__device__ __forceinline__ void topk8_insert(float (&v)[TK], int (&ix)[TK],
                                             float val, int idx) {
    float cv = val; int ci = idx;
#pragma unroll
    for (int i = 0; i < TK; ++i) {
        bool sw = (cv > v[i]) || (cv == v[i] && ci < ix[i]);
        float tv = v[i]; int ti = ix[i];
        v[i]  = sw ? cv : tv;  ix[i] = sw ? ci : ti;
        cv    = sw ? tv : cv;  ci    = sw ? ti : ci;
    }
}

// ---------------------------------------------------------------------------
// K1: q = x@Wq + bq ; k = x@Wk + bk   (f32, W broadcast via uniform loads)
// ---------------------------------------------------------------------------
__global__ __launch_bounds__(256) void proj_kernel(
    const float* __restrict__ x,
    const float* __restrict__ Wq, const float* __restrict__ bq,
    const float* __restrict__ Wk, const float* __restrict__ bk,
    float* __restrict__ q, float* __restrict__ k)
{
    int row = blockIdx.x * 256 + threadIdx.x;        // 0..NT-1
    int cc  = blockIdx.y * 16;                       // combined col 0..255
    bool isK = cc >= CQ;
    const float* W    = isK ? Wk : Wq;
    const float* bias = isK ? bk : bq;
    int c0 = isK ? cc - CQ : cc;

    float acc[16];
#pragma unroll
    for (int j = 0; j < 16; ++j) acc[j] = 0.f;

    const float* xr = x + (size_t)row * DD;
    for (int d0 = 0; d0 < DD; d0 += 4) {
        float4 xv = *reinterpret_cast<const float4*>(xr + d0);
        const float* w0 = W + (size_t)d0 * CQ + c0;
#pragma unroll
        for (int j = 0; j < 16; ++j) {
            acc[j] = fmaf(xv.x, w0[j],        acc[j]);
            acc[j] = fmaf(xv.y, w0[CQ + j],   acc[j]);
            acc[j] = fmaf(xv.z, w0[2*CQ + j], acc[j]);
            acc[j] = fmaf(xv.w, w0[3*CQ + j], acc[j]);
        }
    }
    float* outp = (isK ? k : q) + (size_t)row * CQ + c0;
#pragma unroll
    for (int j = 0; j < 16; ++j) outp[j] = acc[j] + bias[c0 + j];
}

// ---------------------------------------------------------------------------
// K1b: gates = sigmoid(x@Wg + bg)   one wave per row
// ---------------------------------------------------------------------------
__global__ __launch_bounds__(256) void gate_kernel(
    const float* __restrict__ x, const float* __restrict__ Wg,
    const float* __restrict__ bg, float* __restrict__ gout)
{
    int wave = threadIdx.x >> 6, lane = threadIdx.x & 63;
    int row  = blockIdx.x * 4 + wave;
    const float* xr = x + (size_t)row * DD;
    float s = 0.f;
#pragma unroll
    for (int i = 0; i < 4; ++i) {
        int d = (i * 64 + lane) * 4;
        float4 xv = *reinterpret_cast<const float4*>(xr + d);
        float4 wv = *reinterpret_cast<const float4*>(Wg + d);
        s = fmaf(xv.x, wv.x, s); s = fmaf(xv.y, wv.y, s);
        s = fmaf(xv.z, wv.z, s); s = fmaf(xv.w, wv.w, s);
    }
#pragma unroll
    for (int off = 32; off; off >>= 1) s += __shfl_xor(s, off);
    if (lane == 0) gout[row] = 1.f / (1.f + expf(-(s + bg[0])));
}

// ---------------------------------------------------------------------------
// K2: sim + partial top-8.  4 lanes per query (CQ split in quarters):
//   lane = quarter*16 + qloc ; wave handles 16 queries.
// q fragment = 32 VGPRs -> room for double-buffered k prefetch (MLP fix).
// Partial dots combined via shfl_xor(16), shfl_xor(32) butterflies
// (bit-identical on all 4 lanes -> redundant top-k stays consistent).
// ---------------------------------------------------------------------------
__global__ __launch_bounds__(256, 3) void simtopk_kernel(
    const float* __restrict__ q, const float* __restrict__ kmat,
    const float* __restrict__ gates, const float* __restrict__ am,
    float* __restrict__ pv, int* __restrict__ pi)
{
    int wave    = threadIdx.x >> 6;
    int lane    = threadIdx.x & 63;
    int qloc    = lane & 15;            // query within wave
    int quarter = lane >> 4;            // 0..3: which 32-float slice of CQ
    int t  = blockIdx.x * 64 + wave * 16 + qloc;   // global query
    int ch = blockIdx.y;
    int b  = t >> 12;                   // batch (4096 queries each)
    int s0 = ch * SC;

    // q quarter-row: 8 float4 = 32 VGPRs
    float4 qv[8];
    const float4* qp = reinterpret_cast<const float4*>(
        q + (size_t)t * CQ + quarter * 32);
#pragma unroll
    for (int m = 0; m < 8; ++m) qv[m] = qp[m];

    float gate = gates[t];
    float mq   = am[t];

    float v[TK]; int ix[TK];
#pragma unroll
    for (int j = 0; j < TK; ++j) { v[j] = -3.0e38f; ix[j] = 0; }

    const float scale = 0.08838834764831845f;  // 1/sqrt(128)
    const float* kbase = kmat + ((size_t)(b * TT + s0)) * CQ + quarter * 32;

    // prefetch s = s0
    float4 kv[8];
#pragma unroll
    for (int m = 0; m < 8; ++m)
        kv[m] = reinterpret_cast<const float4*>(kbase)[m];

    for (int si = 0; si < SC; ++si) {
        // prefetch next key row while computing this one
        float4 kn[8];
        if (si + 1 < SC) {
            const float4* kp =
                reinterpret_cast<const float4*>(kbase + (size_t)(si + 1) * CQ);
#pragma unroll
            for (int m = 0; m < 8; ++m) kn[m] = kp[m];
        }

        float a0 = 0.f, a1 = 0.f, a2 = 0.f, a3 = 0.f;
#pragma unroll
        for (int m = 0; m < 8; ++m) {
            a0 = fmaf(qv[m].x, kv[m].x, a0);
            a1 = fmaf(qv[m].y, kv[m].y, a1);
            a2 = fmaf(qv[m].z, kv[m].z, a2);
            a3 = fmaf(qv[m].w, kv[m].w, a3);
        }
        float a = (a0 + a1) + (a2 + a3);
        a += __shfl_xor(a, 16);     // combine quarter pairs
        a += __shfl_xor(a, 32);     // all 4 lanes now hold the full dot

        int s = s0 + si;
        float val = a * scale;
        float ms  = am[b * TT + s];
        if (mq * ms == 0.f) val = -1e9f;
        val *= gate;
        if (val > v[TK-1] || (val == v[TK-1] && s < ix[TK-1]))
            topk8_insert(v, ix, val, s);

#pragma unroll
        for (int m = 0; m < 8; ++m) kv[m] = kn[m];
    }

    if (quarter == 0) {
        int base = (t * NCH + ch) * TK;
#pragma unroll
        for (int j = 0; j < TK; ++j) { pv[base + j] = v[j]; pi[base + j] = ix[j]; }
    }
}

// ---------------------------------------------------------------------------
// K3: merge NCH partial top-8 lists -> final top-8; write idx (as float),
// values, and gather x rows. block per query, 256 threads.
// ---------------------------------------------------------------------------
__global__ __launch_bounds__(256) void merge_gather_kernel(
    const float* __restrict__ x,
    const float* __restrict__ pv, const int* __restrict__ pi,
    float* __restrict__ out_g, float* __restrict__ out_i,
    float* __restrict__ out_v)
{
    int t = blockIdx.x;
    __shared__ int sidx[TK];

    if (threadIdx.x == 0) {
        float v[TK]; int ix[TK];
#pragma unroll
        for (int j = 0; j < TK; ++j) { v[j] = -3.0e38f; ix[j] = 0; }
        const float* pvb = pv + (size_t)t * NCH * TK;
        const int*   pib = pi + (size_t)t * NCH * TK;
        for (int c = 0; c < NCH * TK; ++c) {
            float val = pvb[c]; int s = pib[c];
            if (val > v[TK-1] || (val == v[TK-1] && s < ix[TK-1]))
                topk8_insert(v, ix, val, s);
        }
#pragma unroll
        for (int j = 0; j < TK; ++j) {
            out_i[t * TK + j] = (float)ix[j];
            out_v[t * TK + j] = v[j];
            sidx[j] = ix[j];
        }
    }
    __syncthreads();

    int b = t >> 12;
#pragma unroll
    for (int j = 0; j < TK; ++j) {
        int row = sidx[j];
        float4 val = *reinterpret_cast<const float4*>(
            x + ((size_t)(b * TT + row)) * DD + threadIdx.x * 4);
        *reinterpret_cast<float4*>(
            out_g + ((size_t)(t * TK + j)) * DD + threadIdx.x * 4) = val;
    }
}

// ---------------------------------------------------------------------------
extern "C" void kernel_launch(void* const* d_in, const int* in_sizes, int n_in,
                              void* d_out, int out_size, void* d_ws, size_t ws_size,
                              hipStream_t stream) {
    const float* x  = (const float*)d_in[0];
    const float* am = (const float*)d_in[1];
    const float* Wq = (const float*)d_in[2];
    const float* bq = (const float*)d_in[3];
    const float* Wk = (const float*)d_in[4];
    const float* bk = (const float*)d_in[5];
    const float* Wg = (const float*)d_in[6];
    const float* bg = (const float*)d_in[7];

    float* ws = (float*)d_ws;
    float* q  = ws;                              // NT*CQ      = 1048576
    float* k  = ws + 1048576;                    // NT*CQ      = 1048576
    float* g  = ws + 2097152;                    // NT         = 8192
    float* pv = ws + 2105344;                    // NT*NCH*TK  = 1048576
    int*   pi = (int*)(ws + 3153920);            // NT*NCH*TK  = 1048576

    float* out_g = (float*)d_out;                // [B,T,K,D] = 67108864
    float* out_i = out_g + 67108864;             // [B,T,K]   = 65536 (as float)
    float* out_v = out_i + 65536;                // [B,T,K]   = 65536

    proj_kernel<<<dim3(NT / 256, 16), 256, 0, stream>>>(x, Wq, bq, Wk, bk, q, k);
    gate_kernel<<<NT / 4, 256, 0, stream>>>(x, Wg, bg, g);
    simtopk_kernel<<<dim3(NT / 64, NCH), 256, 0, stream>>>(q, k, g, am, pv, pi);
    merge_gather_kernel<<<NT, 256, 0, stream>>>(x, pv, pi, out_g, out_i, out_v);
}